// Round 9
// baseline (572.680 us; speedup 1.0000x reference)
//
#include <hip/hip_runtime.h>

// MsgPassingNN: 3 rounds of edge-MLP + segment_sum + node-MLP.
// N=100000 nodes (D=16), E=3200000 edges.
// fe: 32 -> 9 (relu) -> 9 (relu) -> 9 ; fx: 25 -> 9 (relu) -> 9 (relu) -> 16
//
// R11 = R10 (492us) + L2-resident packing of the random-gather arrays.
//   * Theory: edge kernel stalls on the random base_s gather. Old layout was
//     stride-16 (64B rows) -> 6.4 MB, which does NOT fit a 4 MB per-XCD L2
//     -> thrash (FETCH 93.8 MB/dispatch). New layout: 8 floats packed
//     (32B aligned row, one 64B line) + 9th element in a separate NN array:
//     hot random footprint 3.2 + 0.4 = 3.6 MB < 4 MB -> L2-resident.
//     Same VMEM op count per edge (2x float4 + 1x float). base1 packed the
//     same way (it is L1-friendly: consecutive lanes share d).
//   * Everything else identical to R10: two-level sort (bsort bucket=dst>>7
//     + lsort in-bucket counting sort), weights read via wave-uniform
//     addresses (s_load, zero LDS in edge/node), fe layer-1 hoisted per node,
//     fe layer-3 hoisted to node kernel (m = W3^T sum relu(h2) + deg*b3),
//     branchless edge kernel + wave-segmented scan (ballot/clz), tails
//     atomicAdd 9 sums + free segment count, node writes out in place.

constexpr int NN = 100000;
constexpr int NE = 3200000;
constexpr int NBK = (NN + 127) / 128;      // 782 buckets of 128 nodes
constexpr int SLOT = 8192;                 // sed slots per bucket (avg fill 4096)
constexpr int EPB = 4096;                  // edges per bsort block (16/thread)
constexpr int NBLK_SORT = (NE + EPB - 1) / EPB;   // 782
constexpr int NB_NODE = (NN + 255) / 256;  // 391

// ---------------- pass 1: bucket sort (dst>>7) ----------------
// gcursor[bin] = running count (memset to 0 before launch)

__global__ __launch_bounds__(256) void bsort_k(const int* __restrict__ src,
                                               const int* __restrict__ dst,
                                               int* __restrict__ gcursor,
                                               unsigned* __restrict__ sed)
{
    __shared__ int lhist[NBK];
    __shared__ int lbase[NBK];
    const int t = threadIdx.x;
    for (int i = t; i < NBK; i += 256) lhist[i] = 0;
    __syncthreads();

    const int blkbase = blockIdx.x * EPB;
    unsigned pr[16], sv[16];
    #pragma unroll
    for (int k = 0; k < 16; ++k) {
        const int e = blkbase + k * 256 + t;
        if (e < NE) {
            const int d = dst[e];
            const int s = src[e];
            const int bin = d >> 7;
            const int r = atomicAdd(&lhist[bin], 1);      // LDS atomic
            pr[k] = ((unsigned)bin << 13) | (unsigned)r;  // r < 4096 < 2^13
            sv[k] = ((unsigned)(d & 127) << 17) | (unsigned)s;
        } else {
            pr[k] = 0xFFFFFFFFu;
        }
    }
    __syncthreads();

    for (int i = t; i < NBK; i += 256) {
        const int c = lhist[i];
        if (c) lbase[i] = atomicAdd(&gcursor[i], c);      // offset within bucket
    }
    __syncthreads();

    #pragma unroll
    for (int k = 0; k < 16; ++k) {
        if (pr[k] != 0xFFFFFFFFu) {
            const int bin = (int)(pr[k] >> 13);
            const int r = (int)(pr[k] & 0x1FFFu);
            sed[(size_t)bin * SLOT + lbase[bin] + r] = sv[k];
        }
    }
}

// ---------------- pass 2: in-bucket counting sort by d_local (in place) ----------------

__global__ __launch_bounds__(512) void lsort_k(unsigned* __restrict__ sed,
                                               const int* __restrict__ gcursor)
{
    __shared__ unsigned buf[SLOT];    // 32 KB
    __shared__ unsigned obuf[SLOT];   // 32 KB
    __shared__ int hist[128];
    __shared__ int cur[128];
    const int t = threadIdx.x;
    const int b = blockIdx.x;
    const int base = b * SLOT;
    int fill = gcursor[b];
    if (fill > SLOT) fill = SLOT;     // safety clamp (never hit for this input)

    if (t < 128) hist[t] = 0;
    __syncthreads();
    for (int i = t; i < fill; i += 512) {
        unsigned v = sed[base + i];
        buf[i] = v;
        atomicAdd(&hist[v >> 17], 1);
    }
    __syncthreads();
    // exclusive scan of 128 bins (Hillis-Steele in LDS)
    if (t < 128) cur[t] = hist[t];
    __syncthreads();
    for (int off = 1; off < 128; off <<= 1) {
        int a = (t < 128 && t >= off) ? cur[t - off] : 0;
        __syncthreads();
        if (t < 128) cur[t] += a;
        __syncthreads();
    }
    if (t < 128) cur[t] -= hist[t];   // exclusive prefix
    __syncthreads();
    for (int i = t; i < fill; i += 512) {
        unsigned v = buf[i];
        int r = atomicAdd(&cur[v >> 17], 1);
        obuf[r] = v;
    }
    __syncthreads();
    for (int i = t; i < fill; i += 512) sed[base + i] = obuf[i];
}

// ---------------- round-0 prologue: base1p/d9 + basesp/s9 from X0, zero m ----------------

__global__ __launch_bounds__(256) void base_k(const float* __restrict__ X,
                                              const float* __restrict__ feW1,
                                              const float* __restrict__ feb1,
                                              float* __restrict__ base1p,
                                              float* __restrict__ d9,
                                              float* __restrict__ basesp,
                                              float* __restrict__ s9,
                                              float* __restrict__ m)
{
    const int n = blockIdx.x * 256 + threadIdx.x;
    if (n >= NN) return;

    float x[16];
    const float4* p = reinterpret_cast<const float4*>(X + (size_t)n * 16);
    #pragma unroll
    for (int q = 0; q < 4; ++q) {
        float4 v = p[q];
        x[4*q] = v.x; x[4*q+1] = v.y; x[4*q+2] = v.z; x[4*q+3] = v.w;
    }
    float bd[9];
    #pragma unroll
    for (int j = 0; j < 9; ++j) bd[j] = feb1[j];
    #pragma unroll
    for (int i = 0; i < 16; ++i) {
        const float xi = x[i];
        #pragma unroll
        for (int j = 0; j < 9; ++j) bd[j] = fmaf(xi, feW1[i * 9 + j], bd[j]);
    }
    float bs[9];
    #pragma unroll
    for (int j = 0; j < 9; ++j) bs[j] = 0.f;
    #pragma unroll
    for (int i = 0; i < 16; ++i) {
        const float xi = x[i];
        #pragma unroll
        for (int j = 0; j < 9; ++j) bs[j] = fmaf(xi, feW1[(16 + i) * 9 + j], bs[j]);
    }
    float* bp = base1p + (size_t)n * 8;
    #pragma unroll
    for (int j = 0; j < 8; ++j) bp[j] = bd[j];
    d9[n] = bd[8];
    float* sp = basesp + (size_t)n * 8;
    #pragma unroll
    for (int j = 0; j < 8; ++j) sp[j] = bs[j];
    s9[n] = bs[8];
    float* mp = m + (size_t)n * 10;
    #pragma unroll
    for (int j = 0; j < 10; ++j) mp[j] = 0.f;
}

// ---------------- edge round: 1 thread / sorted slot, wave scan of h2 ----------------
// No LDS, no barrier: weights read via uniform addresses (s_load).
// Random gather arrays (basesp 3.2MB + s9 0.4MB) fit per-XCD L2.

__global__ __launch_bounds__(256) void edge10_k(
    const float* __restrict__ base1p, const float* __restrict__ d9,
    const float* __restrict__ basesp, const float* __restrict__ s9,
    const unsigned* __restrict__ sed,
    const int* __restrict__ gcursor,
    const float* __restrict__ feW2, const float* __restrict__ feb2,
    float* __restrict__ m)    // NN x 10: 9 h2-sums + deg
{
    const int t = threadIdx.x;
    const int b = blockIdx.x >> 5;                 // bucket (SLOT/256 = 32 blocks/bucket)
    const int idx0 = (blockIdx.x & 31) * 256;      // slot offset within bucket
    const int fill = gcursor[b];
    if (idx0 >= fill) return;                      // uniform early exit

    const int idx = idx0 + t;
    const bool valid = idx < fill;
    const int lane = t & 63;
    const int cidx = valid ? idx : fill - 1;       // clamp to a real edge
    const unsigned pk = sed[(size_t)b * SLOT + cidx];
    const int dla = (int)(pk >> 17);               // address-safe d_local
    const int s   = (int)(pk & 0x1FFFFu);
    const int dl  = valid ? dla : 128 + lane;      // sentinel: own segment
    const int dg  = b * 128 + dla;                 // global dst node

    // h1 = relu(base1[d] + base_s[s]); consecutive lanes share d -> L1 hits;
    // basesp/s9 random but L2-resident (3.6 MB < 4 MB per-XCD L2)
    float a[9];
    {
        const float4* pb = reinterpret_cast<const float4*>(base1p + (size_t)dg * 8);
        float4 b0 = pb[0], b1 = pb[1];
        const float b8 = d9[dg];
        const float4* ps = reinterpret_cast<const float4*>(basesp + (size_t)s * 8);
        float4 c0 = ps[0], c1 = ps[1];
        const float c8 = s9[s];
        a[0] = b0.x + c0.x; a[1] = b0.y + c0.y; a[2] = b0.z + c0.z; a[3] = b0.w + c0.w;
        a[4] = b1.x + c1.x; a[5] = b1.y + c1.y; a[6] = b1.z + c1.z; a[7] = b1.w + c1.w;
        a[8] = b8 + c8;
    }
    #pragma unroll
    for (int j = 0; j < 9; ++j) a[j] = fmaxf(a[j], 0.f);

    // h2 = relu(W2^T a + b2); weights via scalar loads (uniform addresses)
    float o[9];
    #pragma unroll
    for (int j = 0; j < 9; ++j) o[j] = feb2[j];
    #pragma unroll
    for (int i = 0; i < 9; ++i) {
        const float ai = a[i];
        #pragma unroll
        for (int j = 0; j < 9; ++j) o[j] = fmaf(ai, feW2[i * 9 + j], o[j]);
    }
    #pragma unroll
    for (int j = 0; j < 9; ++j) o[j] = fmaxf(o[j], 0.f);

    // segmented inclusive scan by dl over the 64-lane wave (dl sorted;
    // invalid lanes are isolated singleton segments -> garbage stays put)
    const int dprev = __shfl_up(dl, 1);
    const bool head = (lane == 0) || (dprev != dl);
    const unsigned long long hm = __ballot(head);
    const int dist = __clzll((long long)(hm << (63 - lane)));  // 0 if head
    #pragma unroll
    for (int off = 1; off < 64; off <<= 1) {
        const bool ok = (dist >= off);
        #pragma unroll
        for (int j = 0; j < 9; ++j) {
            const float ov = __shfl_up(o[j], off);
            o[j] += ok ? ov : 0.f;
        }
    }
    const bool tail = (lane == 63) || (((hm >> (lane + 1)) & 1ull) != 0ull);
    if (tail && valid) {                            // segment tail -> global m
        float* mp = m + (size_t)(b * 128 + dl) * 10;
        #pragma unroll
        for (int j = 0; j < 9; ++j) atomicAdd(mp + j, o[j]);
        atomicAdd(mp + 9, (float)(dist + 1));       // segment length = free count
    }
}

// ---------------- node round: W3/b3 + fx MLP + zero m + next bases ----------------
// No LDS: all weights wave-uniform -> scalar loads from constant cache.

__global__ __launch_bounds__(256) void node9_k(
    const float* __restrict__ Xin, float* __restrict__ m,
    const float* __restrict__ fxW1, const float* __restrict__ fxb1,
    const float* __restrict__ fxW2, const float* __restrict__ fxb2,
    const float* __restrict__ fxW3, const float* __restrict__ fxb3,
    const float* __restrict__ feW1, const float* __restrict__ feb1,
    const float* __restrict__ feW3, const float* __restrict__ feb3,
    float* __restrict__ Xout,
    float* __restrict__ base1p, float* __restrict__ d9,
    float* __restrict__ basesp, float* __restrict__ s9)
{
    const int n = blockIdx.x * 256 + threadIdx.x;
    if (n >= NN) return;

    float xr[16];
    {
        const float4* p = reinterpret_cast<const float4*>(Xin + (size_t)n * 16);
        #pragma unroll
        for (int q = 0; q < 4; ++q) {
            float4 v = p[q];
            xr[4*q] = v.x; xr[4*q+1] = v.y; xr[4*q+2] = v.z; xr[4*q+3] = v.w;
        }
    }
    float S[9], deg;
    float* mp = m + (size_t)n * 10;
    #pragma unroll
    for (int j = 0; j < 9; ++j) S[j] = mp[j];
    deg = mp[9];
    #pragma unroll
    for (int j = 0; j < 10; ++j) mp[j] = 0.f;    // ready for next round

    // m = W3^T S + deg * b3   (fe layer-3, hoisted from the edge loop)
    float mm[9];
    #pragma unroll
    for (int j = 0; j < 9; ++j) mm[j] = deg * feb3[j];
    #pragma unroll
    for (int i = 0; i < 9; ++i) {
        const float si = S[i];
        #pragma unroll
        for (int j = 0; j < 9; ++j) mm[j] = fmaf(si, feW3[i * 9 + j], mm[j]);
    }

    float h1[9];
    #pragma unroll
    for (int j = 0; j < 9; ++j) h1[j] = fxb1[j];
    #pragma unroll
    for (int i = 0; i < 16; ++i) {
        const float xi = xr[i];
        #pragma unroll
        for (int j = 0; j < 9; ++j) h1[j] = fmaf(xi, fxW1[i * 9 + j], h1[j]);
    }
    #pragma unroll
    for (int i = 0; i < 9; ++i) {
        const float xi = mm[i];
        #pragma unroll
        for (int j = 0; j < 9; ++j) h1[j] = fmaf(xi, fxW1[(16 + i) * 9 + j], h1[j]);
    }
    #pragma unroll
    for (int j = 0; j < 9; ++j) h1[j] = fmaxf(h1[j], 0.f);

    float h2[9];
    #pragma unroll
    for (int j = 0; j < 9; ++j) h2[j] = fxb2[j];
    #pragma unroll
    for (int i = 0; i < 9; ++i) {
        const float xi = h1[i];
        #pragma unroll
        for (int j = 0; j < 9; ++j) h2[j] = fmaf(xi, fxW2[i * 9 + j], h2[j]);
    }
    #pragma unroll
    for (int j = 0; j < 9; ++j) h2[j] = fmaxf(h2[j], 0.f);

    float o[16];
    #pragma unroll
    for (int k = 0; k < 16; ++k) o[k] = fxb3[k];
    #pragma unroll
    for (int j = 0; j < 9; ++j) {
        const float hj = h2[j];
        #pragma unroll
        for (int k = 0; k < 16; ++k) o[k] = fmaf(hj, fxW3[j * 16 + k], o[k]);
    }

    float4* po = reinterpret_cast<float4*>(Xout + (size_t)n * 16);
    #pragma unroll
    for (int q = 0; q < 4; ++q) {
        float4 v;
        v.x = o[4*q]; v.y = o[4*q+1]; v.z = o[4*q+2]; v.w = o[4*q+3];
        po[q] = v;
    }

    // base1 / base_s for NEXT round's edge kernel (packed layout)
    float bb[9];
    #pragma unroll
    for (int j = 0; j < 9; ++j) bb[j] = feb1[j];
    #pragma unroll
    for (int i = 0; i < 16; ++i) {
        const float xi = o[i];
        #pragma unroll
        for (int j = 0; j < 9; ++j) bb[j] = fmaf(xi, feW1[i * 9 + j], bb[j]);
    }
    float* bp = base1p + (size_t)n * 8;
    #pragma unroll
    for (int j = 0; j < 8; ++j) bp[j] = bb[j];
    d9[n] = bb[8];

    float cc[9];
    #pragma unroll
    for (int j = 0; j < 9; ++j) cc[j] = 0.f;
    #pragma unroll
    for (int i = 0; i < 16; ++i) {
        const float xi = o[i];
        #pragma unroll
        for (int j = 0; j < 9; ++j) cc[j] = fmaf(xi, feW1[(16 + i) * 9 + j], cc[j]);
    }
    float* sp = basesp + (size_t)n * 8;
    #pragma unroll
    for (int j = 0; j < 8; ++j) sp[j] = cc[j];
    s9[n] = cc[8];
}

extern "C" void kernel_launch(void* const* d_in, const int* in_sizes, int n_in,
                              void* d_out, int out_size, void* d_ws, size_t ws_size,
                              hipStream_t stream)
{
    (void)in_sizes; (void)n_in; (void)out_size; (void)ws_size;
    const float* X0   = (const float*)d_in[0];
    const int*   esrc = (const int*)d_in[1];
    const int*   edst = (const int*)d_in[2];
    const float* feW1 = (const float*)d_in[3];
    const float* feb1 = (const float*)d_in[4];
    const float* feW2 = (const float*)d_in[5];
    const float* feb2 = (const float*)d_in[6];
    const float* feW3 = (const float*)d_in[7];
    const float* feb3 = (const float*)d_in[8];
    const float* fxW1 = (const float*)d_in[9];
    const float* fxb1 = (const float*)d_in[10];
    const float* fxW2 = (const float*)d_in[11];
    const float* fxb2 = (const float*)d_in[12];
    const float* fxW3 = (const float*)d_in[13];
    const float* fxb3 = (const float*)d_in[14];
    float* out = (float*)d_out;

    // workspace layout (floats unless noted). total ~37 MB.
    float* base1p = (float*)d_ws;                         // NN*8  (32B rows)
    float* basesp = base1p + (size_t)NN * 8;              // NN*8  (32B rows, L2-hot)
    float* d9v    = basesp + (size_t)NN * 8;              // NN
    float* s9v    = d9v + NN;                             // NN (L2-hot)
    float* mb     = s9v + NN;                             // NN*10 (9 sums + deg)
    int* gcursor  = (int*)(mb + (size_t)NN * 10);         // NBK (padded to 1024)
    unsigned* sed = (unsigned*)(gcursor + 1024);          // NBK*SLOT u32 = 25.6MB

    const dim3 thr(256);
    const dim3 gS(NBLK_SORT);          // 782
    const dim3 gL(NBK);                // 782
    const dim3 gE(NBK * (SLOT / 256)); // 25024
    const dim3 gN(NB_NODE);            // 391

    // ---- two-level sort (once per launch) ----
    hipMemsetAsync(gcursor, 0, NBK * sizeof(int), stream);
    bsort_k<<<gS, thr, 0, stream>>>(esrc, edst, gcursor, sed);
    lsort_k<<<gL, dim3(512), 0, stream>>>(sed, gcursor);

    // ---- round 0 ----
    base_k<<<gN, thr, 0, stream>>>(X0, feW1, feb1, base1p, d9v, basesp, s9v, mb);
    edge10_k<<<gE, thr, 0, stream>>>(base1p, d9v, basesp, s9v, sed, gcursor,
                                     feW2, feb2, mb);
    node9_k<<<gN, thr, 0, stream>>>(X0, mb, fxW1, fxb1, fxW2, fxb2, fxW3, fxb3,
                                    feW1, feb1, feW3, feb3, out,
                                    base1p, d9v, basesp, s9v);
    // ---- round 1 (node updates out in place; edge never reads X) ----
    edge10_k<<<gE, thr, 0, stream>>>(base1p, d9v, basesp, s9v, sed, gcursor,
                                     feW2, feb2, mb);
    node9_k<<<gN, thr, 0, stream>>>(out, mb, fxW1, fxb1, fxW2, fxb2, fxW3, fxb3,
                                    feW1, feb1, feW3, feb3, out,
                                    base1p, d9v, basesp, s9v);
    // ---- round 2 ----
    edge10_k<<<gE, thr, 0, stream>>>(base1p, d9v, basesp, s9v, sed, gcursor,
                                     feW2, feb2, mb);
    node9_k<<<gN, thr, 0, stream>>>(out, mb, fxW1, fxb1, fxW2, fxb2, fxW3, fxb3,
                                    feW1, feb1, feW3, feb3, out,
                                    base1p, d9v, basesp, s9v);
}

// Round 10
// 550.318 us; speedup vs baseline: 1.0406x; 1.0406x over previous
//
#include <hip/hip_runtime.h>

// MsgPassingNN: 3 rounds of edge-MLP + segment_sum + node-MLP.
// N=100000 nodes (D=16), E=3200000 edges.
// fe: 32 -> 9 (relu) -> 9 (relu) -> 9 ; fx: 25 -> 9 (relu) -> 9 (relu) -> 16
//
// R12 = R10 (492us; R11's split-array packing REVERTED - it doubled random
// line requests and regressed despite 3.5x less HBM fetch) + 2-edges/thread
// pair-aware segmented scan:
//   * Lane l owns sorted slots 2l,2l+1 (one uint2 load). Pairs with d0==d1
//     (~97% at avg degree 32) pre-combine in registers; the 6-step wave scan
//     runs ONCE per 128 edges (was per 64) over pair aggregates keyed by d1,
//     carrying 10 channels (9 h2-sums + element count).
//   * Mid-pair segment boundary (d0!=d1): flush d0's total = o0 +
//     (prev-lane scan if prev key == d0). Run-contiguity of sorted order
//     guarantees middle lanes of a run are never tails -> no double count.
//   * Halves wave count & sed requests, cuts DS ops/edge ~35%, 2 independent
//     gather chains per thread (ILP). Everything else = R10: two-level sort,
//     s_load weights (no LDS in edge/node), fe layer-1 + layer-3 hoisted,
//     base1 stride-12 / bases stride-16 (one 64B line per random gather),
//     node writes out in place.

constexpr int NN = 100000;
constexpr int NE = 3200000;
constexpr int NBK = (NN + 127) / 128;      // 782 buckets of 128 nodes
constexpr int SLOT = 8192;                 // sed slots per bucket (avg fill 4096)
constexpr int EPB = 4096;                  // edges per bsort block (16/thread)
constexpr int NBLK_SORT = (NE + EPB - 1) / EPB;   // 782
constexpr int NB_NODE = (NN + 255) / 256;  // 391

// ---------------- pass 1: bucket sort (dst>>7) ----------------
// gcursor[bin] = running count (memset to 0 before launch)

__global__ __launch_bounds__(256) void bsort_k(const int* __restrict__ src,
                                               const int* __restrict__ dst,
                                               int* __restrict__ gcursor,
                                               unsigned* __restrict__ sed)
{
    __shared__ int lhist[NBK];
    __shared__ int lbase[NBK];
    const int t = threadIdx.x;
    for (int i = t; i < NBK; i += 256) lhist[i] = 0;
    __syncthreads();

    const int blkbase = blockIdx.x * EPB;
    unsigned pr[16], sv[16];
    #pragma unroll
    for (int k = 0; k < 16; ++k) {
        const int e = blkbase + k * 256 + t;
        if (e < NE) {
            const int d = dst[e];
            const int s = src[e];
            const int bin = d >> 7;
            const int r = atomicAdd(&lhist[bin], 1);      // LDS atomic
            pr[k] = ((unsigned)bin << 13) | (unsigned)r;  // r < 4096 < 2^13
            sv[k] = ((unsigned)(d & 127) << 17) | (unsigned)s;
        } else {
            pr[k] = 0xFFFFFFFFu;
        }
    }
    __syncthreads();

    for (int i = t; i < NBK; i += 256) {
        const int c = lhist[i];
        if (c) lbase[i] = atomicAdd(&gcursor[i], c);      // offset within bucket
    }
    __syncthreads();

    #pragma unroll
    for (int k = 0; k < 16; ++k) {
        if (pr[k] != 0xFFFFFFFFu) {
            const int bin = (int)(pr[k] >> 13);
            const int r = (int)(pr[k] & 0x1FFFu);
            sed[(size_t)bin * SLOT + lbase[bin] + r] = sv[k];
        }
    }
}

// ---------------- pass 2: in-bucket counting sort by d_local (in place) ----------------

__global__ __launch_bounds__(512) void lsort_k(unsigned* __restrict__ sed,
                                               const int* __restrict__ gcursor)
{
    __shared__ unsigned buf[SLOT];    // 32 KB
    __shared__ unsigned obuf[SLOT];   // 32 KB
    __shared__ int hist[128];
    __shared__ int cur[128];
    const int t = threadIdx.x;
    const int b = blockIdx.x;
    const int base = b * SLOT;
    int fill = gcursor[b];
    if (fill > SLOT) fill = SLOT;     // safety clamp (never hit for this input)

    if (t < 128) hist[t] = 0;
    __syncthreads();
    for (int i = t; i < fill; i += 512) {
        unsigned v = sed[base + i];
        buf[i] = v;
        atomicAdd(&hist[v >> 17], 1);
    }
    __syncthreads();
    // exclusive scan of 128 bins (Hillis-Steele in LDS)
    if (t < 128) cur[t] = hist[t];
    __syncthreads();
    for (int off = 1; off < 128; off <<= 1) {
        int a = (t < 128 && t >= off) ? cur[t - off] : 0;
        __syncthreads();
        if (t < 128) cur[t] += a;
        __syncthreads();
    }
    if (t < 128) cur[t] -= hist[t];   // exclusive prefix
    __syncthreads();
    for (int i = t; i < fill; i += 512) {
        unsigned v = buf[i];
        int r = atomicAdd(&cur[v >> 17], 1);
        obuf[r] = v;
    }
    __syncthreads();
    for (int i = t; i < fill; i += 512) sed[base + i] = obuf[i];
}

// ---------------- round-0 prologue: base1 + base_s from X0, zero m ----------------

__global__ __launch_bounds__(256) void base_k(const float* __restrict__ X,
                                              const float* __restrict__ feW1,
                                              const float* __restrict__ feb1,
                                              float* __restrict__ base1,
                                              float* __restrict__ bases,
                                              float* __restrict__ m)
{
    const int n = blockIdx.x * 256 + threadIdx.x;
    if (n >= NN) return;

    float x[16];
    const float4* p = reinterpret_cast<const float4*>(X + (size_t)n * 16);
    #pragma unroll
    for (int q = 0; q < 4; ++q) {
        float4 v = p[q];
        x[4*q] = v.x; x[4*q+1] = v.y; x[4*q+2] = v.z; x[4*q+3] = v.w;
    }
    float bd[9];
    #pragma unroll
    for (int j = 0; j < 9; ++j) bd[j] = feb1[j];
    #pragma unroll
    for (int i = 0; i < 16; ++i) {
        const float xi = x[i];
        #pragma unroll
        for (int j = 0; j < 9; ++j) bd[j] = fmaf(xi, feW1[i * 9 + j], bd[j]);
    }
    float bs[9];
    #pragma unroll
    for (int j = 0; j < 9; ++j) bs[j] = 0.f;
    #pragma unroll
    for (int i = 0; i < 16; ++i) {
        const float xi = x[i];
        #pragma unroll
        for (int j = 0; j < 9; ++j) bs[j] = fmaf(xi, feW1[(16 + i) * 9 + j], bs[j]);
    }
    float* bp = base1 + (size_t)n * 12;
    #pragma unroll
    for (int j = 0; j < 9; ++j) bp[j] = bd[j];
    float* sp = bases + (size_t)n * 16;
    #pragma unroll
    for (int j = 0; j < 9; ++j) sp[j] = bs[j];
    float* mp = m + (size_t)n * 10;
    #pragma unroll
    for (int j = 0; j < 10; ++j) mp[j] = 0.f;
}

// ---------------- edge round: 2 edges/thread, pair-aware wave scan ----------------
// No LDS, no barrier: weights read via uniform addresses (s_load).

__global__ __launch_bounds__(256) void edge11_k(
    const float* __restrict__ base1,
    const float* __restrict__ bases,
    const unsigned* __restrict__ sed,
    const int* __restrict__ gcursor,
    const float* __restrict__ feW2, const float* __restrict__ feb2,
    float* __restrict__ m)    // NN x 10: 9 h2-sums + deg
{
    const int t = threadIdx.x;
    const int b = blockIdx.x >> 4;                 // bucket (16 blocks/bucket)
    const int idx0 = (blockIdx.x & 15) * 512;      // block covers 512 slots
    const int fill = gcursor[b];
    if (idx0 >= fill) return;                      // block-uniform early exit

    const int lane = t & 63;
    const int start = idx0 + (t >> 6) * 128;       // this wave's 128 slots
    if (start >= fill) return;                     // wave-uniform early exit

    const int e0 = start + 2 * lane;
    const bool v0 = e0 < fill;
    const bool v1 = e0 + 1 < fill;

    // pair load (8B aligned; always within the bucket's SLOT region)
    const uint2 pk = *reinterpret_cast<const uint2*>(sed + (size_t)b * SLOT + e0);
    const int d0 = (int)(pk.x >> 17);
    const int d1 = (int)(pk.y >> 17);
    int s0 = (int)(pk.x & 0x1FFFFu);  s0 = s0 < NN ? s0 : NN - 1;  // garbage-safe
    int s1 = (int)(pk.y & 0x1FFFFu);  s1 = s1 < NN ? s1 : NN - 1;
    const int k0 = v0 ? d0 : (160 + 2 * lane);     // unique sentinels (>=160,
    const int k1 = v1 ? d1 : (161 + 2 * lane);     //  even/odd split, never merge)

    // ---- edge 0: h1 = relu(base1[d0] + bases[s0]); h2 = relu(W2^T h1 + b2)
    float o0[9], o1[9];
    {
        const float4* pb = reinterpret_cast<const float4*>(base1 + (size_t)(b * 128 + d0) * 12);
        float4 b0 = pb[0], b1 = pb[1];
        const float b8 = base1[(size_t)(b * 128 + d0) * 12 + 8];
        const float4* ps = reinterpret_cast<const float4*>(bases + (size_t)s0 * 16);
        float4 c0 = ps[0], c1 = ps[1];
        const float c8 = bases[(size_t)s0 * 16 + 8];
        float a[9];
        a[0] = b0.x + c0.x; a[1] = b0.y + c0.y; a[2] = b0.z + c0.z; a[3] = b0.w + c0.w;
        a[4] = b1.x + c1.x; a[5] = b1.y + c1.y; a[6] = b1.z + c1.z; a[7] = b1.w + c1.w;
        a[8] = b8 + c8;
        #pragma unroll
        for (int j = 0; j < 9; ++j) a[j] = fmaxf(a[j], 0.f);
        #pragma unroll
        for (int j = 0; j < 9; ++j) o0[j] = feb2[j];
        #pragma unroll
        for (int i = 0; i < 9; ++i) {
            const float ai = a[i];
            #pragma unroll
            for (int j = 0; j < 9; ++j) o0[j] = fmaf(ai, feW2[i * 9 + j], o0[j]);
        }
        #pragma unroll
        for (int j = 0; j < 9; ++j) o0[j] = fmaxf(o0[j], 0.f);
    }
    // ---- edge 1
    {
        const float4* pb = reinterpret_cast<const float4*>(base1 + (size_t)(b * 128 + d1) * 12);
        float4 b0 = pb[0], b1 = pb[1];
        const float b8 = base1[(size_t)(b * 128 + d1) * 12 + 8];
        const float4* ps = reinterpret_cast<const float4*>(bases + (size_t)s1 * 16);
        float4 c0 = ps[0], c1 = ps[1];
        const float c8 = bases[(size_t)s1 * 16 + 8];
        float a[9];
        a[0] = b0.x + c0.x; a[1] = b0.y + c0.y; a[2] = b0.z + c0.z; a[3] = b0.w + c0.w;
        a[4] = b1.x + c1.x; a[5] = b1.y + c1.y; a[6] = b1.z + c1.z; a[7] = b1.w + c1.w;
        a[8] = b8 + c8;
        #pragma unroll
        for (int j = 0; j < 9; ++j) a[j] = fmaxf(a[j], 0.f);
        #pragma unroll
        for (int j = 0; j < 9; ++j) o1[j] = feb2[j];
        #pragma unroll
        for (int i = 0; i < 9; ++i) {
            const float ai = a[i];
            #pragma unroll
            for (int j = 0; j < 9; ++j) o1[j] = fmaf(ai, feW2[i * 9 + j], o1[j]);
        }
        #pragma unroll
        for (int j = 0; j < 9; ++j) o1[j] = fmaxf(o1[j], 0.f);
    }

    // ---- pair aggregate keyed by k1 (10 channels: 9 sums + count)
    const bool same = (k0 == k1);                  // same implies both valid
    float S[10];
    #pragma unroll
    for (int j = 0; j < 9; ++j) S[j] = same ? (o0[j] + o1[j]) : o1[j];
    S[9] = same ? 2.f : (v1 ? 1.f : 0.f);

    // ---- segmented inclusive scan over pair-aggregates (key = k1)
    const int pkey = __shfl_up(k1, 1);
    const bool head = (lane == 0) || (pkey != k1);
    const unsigned long long hm = __ballot(head);
    const int dist = __clzll((long long)(hm << (63 - lane)));  // 0 if head
    #pragma unroll
    for (int off = 1; off < 64; off <<= 1) {
        const bool ok = (dist >= off);
        #pragma unroll
        for (int j = 0; j < 10; ++j) {
            const float ov = __shfl_up(S[j], off);
            S[j] += ok ? ov : 0.f;
        }
    }
    // previous lane's scan value (for mid-pair boundary linkage)
    float P[10];
    #pragma unroll
    for (int j = 0; j < 10; ++j) P[j] = __shfl_up(S[j], 1);

    // ---- Flush A: mid-pair boundary (d0's segment ends at this pair's e0)
    if (!same && v0) {
        const bool link = (lane > 0) && (pkey == k0);
        float* mp = m + (size_t)(b * 128 + d0) * 10;
        #pragma unroll
        for (int j = 0; j < 9; ++j) atomicAdd(mp + j, (link ? P[j] : 0.f) + o0[j]);
        atomicAdd(mp + 9, (link ? P[9] : 0.f) + 1.f);
    }
    // ---- Flush B: lane-boundary tail (segment of k1 ends at this lane)
    const int nk0 = __shfl_down(k0, 1);
    const bool tail = v1 && ((lane == 63) || (nk0 != k1));
    if (tail) {
        float* mp = m + (size_t)(b * 128 + d1) * 10;
        #pragma unroll
        for (int j = 0; j < 9; ++j) atomicAdd(mp + j, S[j]);
        atomicAdd(mp + 9, S[9]);
    }
}

// ---------------- node round: W3/b3 + fx MLP + zero m + next bases ----------------
// No LDS: all weights wave-uniform -> scalar loads from constant cache.

__global__ __launch_bounds__(256) void node8_k(
    const float* __restrict__ Xin, float* __restrict__ m,
    const float* __restrict__ fxW1, const float* __restrict__ fxb1,
    const float* __restrict__ fxW2, const float* __restrict__ fxb2,
    const float* __restrict__ fxW3, const float* __restrict__ fxb3,
    const float* __restrict__ feW1, const float* __restrict__ feb1,
    const float* __restrict__ feW3, const float* __restrict__ feb3,
    float* __restrict__ Xout, float* __restrict__ base1out,
    float* __restrict__ basesout)
{
    const int n = blockIdx.x * 256 + threadIdx.x;
    if (n >= NN) return;

    float xr[16];
    {
        const float4* p = reinterpret_cast<const float4*>(Xin + (size_t)n * 16);
        #pragma unroll
        for (int q = 0; q < 4; ++q) {
            float4 v = p[q];
            xr[4*q] = v.x; xr[4*q+1] = v.y; xr[4*q+2] = v.z; xr[4*q+3] = v.w;
        }
    }
    float S[9], deg;
    float* mp = m + (size_t)n * 10;
    #pragma unroll
    for (int j = 0; j < 9; ++j) S[j] = mp[j];
    deg = mp[9];
    #pragma unroll
    for (int j = 0; j < 10; ++j) mp[j] = 0.f;    // ready for next round

    // m = W3^T S + deg * b3   (fe layer-3, hoisted from the edge loop)
    float mm[9];
    #pragma unroll
    for (int j = 0; j < 9; ++j) mm[j] = deg * feb3[j];
    #pragma unroll
    for (int i = 0; i < 9; ++i) {
        const float si = S[i];
        #pragma unroll
        for (int j = 0; j < 9; ++j) mm[j] = fmaf(si, feW3[i * 9 + j], mm[j]);
    }

    float h1[9];
    #pragma unroll
    for (int j = 0; j < 9; ++j) h1[j] = fxb1[j];
    #pragma unroll
    for (int i = 0; i < 16; ++i) {
        const float xi = xr[i];
        #pragma unroll
        for (int j = 0; j < 9; ++j) h1[j] = fmaf(xi, fxW1[i * 9 + j], h1[j]);
    }
    #pragma unroll
    for (int i = 0; i < 9; ++i) {
        const float xi = mm[i];
        #pragma unroll
        for (int j = 0; j < 9; ++j) h1[j] = fmaf(xi, fxW1[(16 + i) * 9 + j], h1[j]);
    }
    #pragma unroll
    for (int j = 0; j < 9; ++j) h1[j] = fmaxf(h1[j], 0.f);

    float h2[9];
    #pragma unroll
    for (int j = 0; j < 9; ++j) h2[j] = fxb2[j];
    #pragma unroll
    for (int i = 0; i < 9; ++i) {
        const float xi = h1[i];
        #pragma unroll
        for (int j = 0; j < 9; ++j) h2[j] = fmaf(xi, fxW2[i * 9 + j], h2[j]);
    }
    #pragma unroll
    for (int j = 0; j < 9; ++j) h2[j] = fmaxf(h2[j], 0.f);

    float o[16];
    #pragma unroll
    for (int k = 0; k < 16; ++k) o[k] = fxb3[k];
    #pragma unroll
    for (int j = 0; j < 9; ++j) {
        const float hj = h2[j];
        #pragma unroll
        for (int k = 0; k < 16; ++k) o[k] = fmaf(hj, fxW3[j * 16 + k], o[k]);
    }

    float4* po = reinterpret_cast<float4*>(Xout + (size_t)n * 16);
    #pragma unroll
    for (int q = 0; q < 4; ++q) {
        float4 v;
        v.x = o[4*q]; v.y = o[4*q+1]; v.z = o[4*q+2]; v.w = o[4*q+3];
        po[q] = v;
    }

    // base1 / base_s for NEXT round's edge kernel
    float bb[9];
    #pragma unroll
    for (int j = 0; j < 9; ++j) bb[j] = feb1[j];
    #pragma unroll
    for (int i = 0; i < 16; ++i) {
        const float xi = o[i];
        #pragma unroll
        for (int j = 0; j < 9; ++j) bb[j] = fmaf(xi, feW1[i * 9 + j], bb[j]);
    }
    float* bp = base1out + (size_t)n * 12;
    #pragma unroll
    for (int j = 0; j < 9; ++j) bp[j] = bb[j];

    float cc[9];
    #pragma unroll
    for (int j = 0; j < 9; ++j) cc[j] = 0.f;
    #pragma unroll
    for (int i = 0; i < 16; ++i) {
        const float xi = o[i];
        #pragma unroll
        for (int j = 0; j < 9; ++j) cc[j] = fmaf(xi, feW1[(16 + i) * 9 + j], cc[j]);
    }
    float* sp = basesout + (size_t)n * 16;
    #pragma unroll
    for (int j = 0; j < 9; ++j) sp[j] = cc[j];
}

extern "C" void kernel_launch(void* const* d_in, const int* in_sizes, int n_in,
                              void* d_out, int out_size, void* d_ws, size_t ws_size,
                              hipStream_t stream)
{
    (void)in_sizes; (void)n_in; (void)out_size; (void)ws_size;
    const float* X0   = (const float*)d_in[0];
    const int*   esrc = (const int*)d_in[1];
    const int*   edst = (const int*)d_in[2];
    const float* feW1 = (const float*)d_in[3];
    const float* feb1 = (const float*)d_in[4];
    const float* feW2 = (const float*)d_in[5];
    const float* feb2 = (const float*)d_in[6];
    const float* feW3 = (const float*)d_in[7];
    const float* feb3 = (const float*)d_in[8];
    const float* fxW1 = (const float*)d_in[9];
    const float* fxb1 = (const float*)d_in[10];
    const float* fxW2 = (const float*)d_in[11];
    const float* fxb2 = (const float*)d_in[12];
    const float* fxW3 = (const float*)d_in[13];
    const float* fxb3 = (const float*)d_in[14];
    float* out = (float*)d_out;

    // workspace layout (floats unless noted). total ~41 MB.
    float* base1  = (float*)d_ws;                         // NN*12
    float* bases  = base1 + (size_t)NN * 12;              // NN*16 (64B rows)
    float* mb     = bases + (size_t)NN * 16;              // NN*10 (9 sums + deg)
    int* gcursor  = (int*)(mb + (size_t)NN * 10);         // NBK (padded to 1024)
    unsigned* sed = (unsigned*)(gcursor + 1024);          // NBK*SLOT u32 = 25.6MB

    const dim3 thr(256);
    const dim3 gS(NBLK_SORT);          // 782
    const dim3 gL(NBK);                // 782
    const dim3 gE(NBK * (SLOT / 512)); // 12512 (2 edges/thread)
    const dim3 gN(NB_NODE);            // 391

    // ---- two-level sort (once per launch) ----
    hipMemsetAsync(gcursor, 0, NBK * sizeof(int), stream);
    bsort_k<<<gS, thr, 0, stream>>>(esrc, edst, gcursor, sed);
    lsort_k<<<gL, dim3(512), 0, stream>>>(sed, gcursor);

    // ---- round 0 ----
    base_k<<<gN, thr, 0, stream>>>(X0, feW1, feb1, base1, bases, mb);
    edge11_k<<<gE, thr, 0, stream>>>(base1, bases, sed, gcursor, feW2, feb2, mb);
    node8_k<<<gN, thr, 0, stream>>>(X0, mb, fxW1, fxb1, fxW2, fxb2, fxW3, fxb3,
                                    feW1, feb1, feW3, feb3, out, base1, bases);
    // ---- round 1 (node updates out in place; edge never reads X) ----
    edge11_k<<<gE, thr, 0, stream>>>(base1, bases, sed, gcursor, feW2, feb2, mb);
    node8_k<<<gN, thr, 0, stream>>>(out, mb, fxW1, fxb1, fxW2, fxb2, fxW3, fxb3,
                                    feW1, feb1, feW3, feb3, out, base1, bases);
    // ---- round 2 ----
    edge11_k<<<gE, thr, 0, stream>>>(base1, bases, sed, gcursor, feW2, feb2, mb);
    node8_k<<<gN, thr, 0, stream>>>(out, mb, fxW1, fxb1, fxW2, fxb2, fxW3, fxb3,
                                    feW1, feb1, feW3, feb3, out, base1, bases);
}

// Round 11
// 497.574 us; speedup vs baseline: 1.1509x; 1.1060x over previous
//
#include <hip/hip_runtime.h>

// MsgPassingNN: 3 rounds of edge-MLP + segment_sum + node-MLP.
// N=100000 nodes (D=16), E=3200000 edges.
// fe: 32 -> 9 (relu) -> 9 (relu) -> 9 ; fx: 25 -> 9 (relu) -> 9 (relu) -> 16
//
// R13 = R10 (best verified: 492us) + three local wins. R11 (split arrays)
// and R12 (2-edges/thread) both REVERTED — the edge kernel is latency-bound
// and lives on maximal wave count + one random line per gather.
//   * m rows stride 16 (64B-aligned): tail-atomic group always hits ONE
//     cache line (was 40B@stride-40, straddling 2 lines 60% of the time);
//     node reads/zeroes m with float4s.
//   * edge grid 24 blocks/bucket (was 32): fill ~ Poisson(4096), 6144 slots
//     is a +32-sigma bound -> blocks 24..31 were always empty dispatches.
//   * everything else byte-identical to R10: 1 thread/edge, u32 sed
//     (d_local:7|src:17), two-level sort (bsort bucket=dst>>7 + lsort
//     in-bucket counting sort), weights via wave-uniform s_load (zero LDS
//     in edge/node), fe layer-1 hoisted per node (base1 stride 12,
//     bases stride 16 = one 64B line per random gather), fe layer-3 hoisted
//     to node (m = W3^T sum relu(h2) + deg*b3, deg free from ballot mask),
//     branchless edge + wave-segmented scan, node writes out in place.

constexpr int NN = 100000;
constexpr int NE = 3200000;
constexpr int NBK = (NN + 127) / 128;      // 782 buckets of 128 nodes
constexpr int SLOT = 8192;                 // sed slots per bucket (avg fill 4096)
constexpr int EPB = 4096;                  // edges per bsort block (16/thread)
constexpr int NBLK_SORT = (NE + EPB - 1) / EPB;   // 782
constexpr int NB_NODE = (NN + 255) / 256;  // 391
constexpr int BPB = 24;                    // edge blocks per bucket (covers 6144)

// ---------------- pass 1: bucket sort (dst>>7) ----------------
// gcursor[bin] = running count (memset to 0 before launch)

__global__ __launch_bounds__(256) void bsort_k(const int* __restrict__ src,
                                               const int* __restrict__ dst,
                                               int* __restrict__ gcursor,
                                               unsigned* __restrict__ sed)
{
    __shared__ int lhist[NBK];
    __shared__ int lbase[NBK];
    const int t = threadIdx.x;
    for (int i = t; i < NBK; i += 256) lhist[i] = 0;
    __syncthreads();

    const int blkbase = blockIdx.x * EPB;
    unsigned pr[16], sv[16];
    #pragma unroll
    for (int k = 0; k < 16; ++k) {
        const int e = blkbase + k * 256 + t;
        if (e < NE) {
            const int d = dst[e];
            const int s = src[e];
            const int bin = d >> 7;
            const int r = atomicAdd(&lhist[bin], 1);      // LDS atomic
            pr[k] = ((unsigned)bin << 13) | (unsigned)r;  // r < 4096 < 2^13
            sv[k] = ((unsigned)(d & 127) << 17) | (unsigned)s;
        } else {
            pr[k] = 0xFFFFFFFFu;
        }
    }
    __syncthreads();

    for (int i = t; i < NBK; i += 256) {
        const int c = lhist[i];
        if (c) lbase[i] = atomicAdd(&gcursor[i], c);      // offset within bucket
    }
    __syncthreads();

    #pragma unroll
    for (int k = 0; k < 16; ++k) {
        if (pr[k] != 0xFFFFFFFFu) {
            const int bin = (int)(pr[k] >> 13);
            const int r = (int)(pr[k] & 0x1FFFu);
            sed[(size_t)bin * SLOT + lbase[bin] + r] = sv[k];
        }
    }
}

// ---------------- pass 2: in-bucket counting sort by d_local (in place) ----------------

__global__ __launch_bounds__(512) void lsort_k(unsigned* __restrict__ sed,
                                               const int* __restrict__ gcursor)
{
    __shared__ unsigned buf[SLOT];    // 32 KB
    __shared__ unsigned obuf[SLOT];   // 32 KB
    __shared__ int hist[128];
    __shared__ int cur[128];
    const int t = threadIdx.x;
    const int b = blockIdx.x;
    const int base = b * SLOT;
    int fill = gcursor[b];
    if (fill > SLOT) fill = SLOT;     // safety clamp (never hit for this input)

    if (t < 128) hist[t] = 0;
    __syncthreads();
    for (int i = t; i < fill; i += 512) {
        unsigned v = sed[base + i];
        buf[i] = v;
        atomicAdd(&hist[v >> 17], 1);
    }
    __syncthreads();
    // exclusive scan of 128 bins (Hillis-Steele in LDS)
    if (t < 128) cur[t] = hist[t];
    __syncthreads();
    for (int off = 1; off < 128; off <<= 1) {
        int a = (t < 128 && t >= off) ? cur[t - off] : 0;
        __syncthreads();
        if (t < 128) cur[t] += a;
        __syncthreads();
    }
    if (t < 128) cur[t] -= hist[t];   // exclusive prefix
    __syncthreads();
    for (int i = t; i < fill; i += 512) {
        unsigned v = buf[i];
        int r = atomicAdd(&cur[v >> 17], 1);
        obuf[r] = v;
    }
    __syncthreads();
    for (int i = t; i < fill; i += 512) sed[base + i] = obuf[i];
}

// ---------------- round-0 prologue: base1 + base_s from X0, zero m ----------------

__global__ __launch_bounds__(256) void base_k(const float* __restrict__ X,
                                              const float* __restrict__ feW1,
                                              const float* __restrict__ feb1,
                                              float* __restrict__ base1,
                                              float* __restrict__ bases,
                                              float* __restrict__ m)
{
    const int n = blockIdx.x * 256 + threadIdx.x;
    if (n >= NN) return;

    float x[16];
    const float4* p = reinterpret_cast<const float4*>(X + (size_t)n * 16);
    #pragma unroll
    for (int q = 0; q < 4; ++q) {
        float4 v = p[q];
        x[4*q] = v.x; x[4*q+1] = v.y; x[4*q+2] = v.z; x[4*q+3] = v.w;
    }
    float bd[9];
    #pragma unroll
    for (int j = 0; j < 9; ++j) bd[j] = feb1[j];
    #pragma unroll
    for (int i = 0; i < 16; ++i) {
        const float xi = x[i];
        #pragma unroll
        for (int j = 0; j < 9; ++j) bd[j] = fmaf(xi, feW1[i * 9 + j], bd[j]);
    }
    float bs[9];
    #pragma unroll
    for (int j = 0; j < 9; ++j) bs[j] = 0.f;
    #pragma unroll
    for (int i = 0; i < 16; ++i) {
        const float xi = x[i];
        #pragma unroll
        for (int j = 0; j < 9; ++j) bs[j] = fmaf(xi, feW1[(16 + i) * 9 + j], bs[j]);
    }
    float* bp = base1 + (size_t)n * 12;
    #pragma unroll
    for (int j = 0; j < 9; ++j) bp[j] = bd[j];
    float* sp = bases + (size_t)n * 16;
    #pragma unroll
    for (int j = 0; j < 9; ++j) sp[j] = bs[j];
    // zero m (stride-16 rows, 64B aligned): 4 float4 stores
    float4* mp4 = reinterpret_cast<float4*>(m + (size_t)n * 16);
    const float4 z = {0.f, 0.f, 0.f, 0.f};
    #pragma unroll
    for (int q = 0; q < 4; ++q) mp4[q] = z;
}

// ---------------- edge round: 1 thread / sorted slot, wave scan of h2 ----------------
// No LDS, no barrier: weights read via uniform addresses (s_load).

__global__ __launch_bounds__(256) void edge12_k(
    const float* __restrict__ base1,
    const float* __restrict__ bases,
    const unsigned* __restrict__ sed,
    const int* __restrict__ gcursor,
    const float* __restrict__ feW2, const float* __restrict__ feb2,
    float* __restrict__ m)    // NN x 16 rows (64B): 9 h2-sums + deg + pad
{
    const int t = threadIdx.x;
    const int b = blockIdx.x / BPB;                // bucket
    const int idx0 = (blockIdx.x - b * BPB) * 256; // slot offset within bucket
    const int fill = gcursor[b];
    if (idx0 >= fill) return;                      // uniform early exit

    const int idx = idx0 + t;
    const bool valid = idx < fill;
    const int lane = t & 63;
    const int cidx = valid ? idx : fill - 1;       // clamp to a real edge
    const unsigned pk = sed[(size_t)b * SLOT + cidx];
    const int dla = (int)(pk >> 17);               // address-safe d_local
    const int s   = (int)(pk & 0x1FFFFu);
    const int dl  = valid ? dla : 128 + lane;      // sentinel: own segment

    // h1 = relu(base1[d] + base_s[s]); consecutive lanes share d -> L1 hits
    float a[9];
    {
        const float4* pb = reinterpret_cast<const float4*>(base1 + (size_t)(b * 128 + dla) * 12);
        float4 b0 = pb[0], b1 = pb[1];
        const float b8 = base1[(size_t)(b * 128 + dla) * 12 + 8];
        const float4* ps = reinterpret_cast<const float4*>(bases + (size_t)s * 16);
        float4 c0 = ps[0], c1 = ps[1];
        const float c8 = bases[(size_t)s * 16 + 8];
        a[0] = b0.x + c0.x; a[1] = b0.y + c0.y; a[2] = b0.z + c0.z; a[3] = b0.w + c0.w;
        a[4] = b1.x + c1.x; a[5] = b1.y + c1.y; a[6] = b1.z + c1.z; a[7] = b1.w + c1.w;
        a[8] = b8 + c8;
    }
    #pragma unroll
    for (int j = 0; j < 9; ++j) a[j] = fmaxf(a[j], 0.f);

    // h2 = relu(W2^T a + b2); weights via scalar loads (uniform addresses)
    float o[9];
    #pragma unroll
    for (int j = 0; j < 9; ++j) o[j] = feb2[j];
    #pragma unroll
    for (int i = 0; i < 9; ++i) {
        const float ai = a[i];
        #pragma unroll
        for (int j = 0; j < 9; ++j) o[j] = fmaf(ai, feW2[i * 9 + j], o[j]);
    }
    #pragma unroll
    for (int j = 0; j < 9; ++j) o[j] = fmaxf(o[j], 0.f);

    // segmented inclusive scan by dl over the 64-lane wave (dl sorted;
    // invalid lanes are isolated singleton segments -> garbage stays put)
    const int dprev = __shfl_up(dl, 1);
    const bool head = (lane == 0) || (dprev != dl);
    const unsigned long long hm = __ballot(head);
    const int dist = __clzll((long long)(hm << (63 - lane)));  // 0 if head
    #pragma unroll
    for (int off = 1; off < 64; off <<= 1) {
        const bool ok = (dist >= off);
        #pragma unroll
        for (int j = 0; j < 9; ++j) {
            const float ov = __shfl_up(o[j], off);
            o[j] += ok ? ov : 0.f;
        }
    }
    const bool tail = (lane == 63) || (((hm >> (lane + 1)) & 1ull) != 0ull);
    if (tail && valid) {                            // segment tail -> global m
        float* mp = m + (size_t)(b * 128 + dl) * 16;   // one 64B line
        #pragma unroll
        for (int j = 0; j < 9; ++j) atomicAdd(mp + j, o[j]);
        atomicAdd(mp + 9, (float)(dist + 1));       // segment length = free count
    }
}

// ---------------- node round: W3/b3 + fx MLP + zero m + next bases ----------------
// No LDS: all weights wave-uniform -> scalar loads from constant cache.

__global__ __launch_bounds__(256) void node10_k(
    const float* __restrict__ Xin, float* __restrict__ m,
    const float* __restrict__ fxW1, const float* __restrict__ fxb1,
    const float* __restrict__ fxW2, const float* __restrict__ fxb2,
    const float* __restrict__ fxW3, const float* __restrict__ fxb3,
    const float* __restrict__ feW1, const float* __restrict__ feb1,
    const float* __restrict__ feW3, const float* __restrict__ feb3,
    float* __restrict__ Xout, float* __restrict__ base1out,
    float* __restrict__ basesout)
{
    const int n = blockIdx.x * 256 + threadIdx.x;
    if (n >= NN) return;

    float xr[16];
    {
        const float4* p = reinterpret_cast<const float4*>(Xin + (size_t)n * 16);
        #pragma unroll
        for (int q = 0; q < 4; ++q) {
            float4 v = p[q];
            xr[4*q] = v.x; xr[4*q+1] = v.y; xr[4*q+2] = v.z; xr[4*q+3] = v.w;
        }
    }
    // m row (stride 16, 64B): S[0..8] + deg at [9]
    float S[9], deg;
    float* mp = m + (size_t)n * 16;
    {
        float4* mp4 = reinterpret_cast<float4*>(mp);
        float4 v0 = mp4[0], v1 = mp4[1], v2 = mp4[2];
        S[0] = v0.x; S[1] = v0.y; S[2] = v0.z; S[3] = v0.w;
        S[4] = v1.x; S[5] = v1.y; S[6] = v1.z; S[7] = v1.w;
        S[8] = v2.x; deg = v2.y;
        const float4 z = {0.f, 0.f, 0.f, 0.f};
        #pragma unroll
        for (int q = 0; q < 4; ++q) mp4[q] = z;      // ready for next round
    }

    // m = W3^T S + deg * b3   (fe layer-3, hoisted from the edge loop)
    float mm[9];
    #pragma unroll
    for (int j = 0; j < 9; ++j) mm[j] = deg * feb3[j];
    #pragma unroll
    for (int i = 0; i < 9; ++i) {
        const float si = S[i];
        #pragma unroll
        for (int j = 0; j < 9; ++j) mm[j] = fmaf(si, feW3[i * 9 + j], mm[j]);
    }

    float h1[9];
    #pragma unroll
    for (int j = 0; j < 9; ++j) h1[j] = fxb1[j];
    #pragma unroll
    for (int i = 0; i < 16; ++i) {
        const float xi = xr[i];
        #pragma unroll
        for (int j = 0; j < 9; ++j) h1[j] = fmaf(xi, fxW1[i * 9 + j], h1[j]);
    }
    #pragma unroll
    for (int i = 0; i < 9; ++i) {
        const float xi = mm[i];
        #pragma unroll
        for (int j = 0; j < 9; ++j) h1[j] = fmaf(xi, fxW1[(16 + i) * 9 + j], h1[j]);
    }
    #pragma unroll
    for (int j = 0; j < 9; ++j) h1[j] = fmaxf(h1[j], 0.f);

    float h2[9];
    #pragma unroll
    for (int j = 0; j < 9; ++j) h2[j] = fxb2[j];
    #pragma unroll
    for (int i = 0; i < 9; ++i) {
        const float xi = h1[i];
        #pragma unroll
        for (int j = 0; j < 9; ++j) h2[j] = fmaf(xi, fxW2[i * 9 + j], h2[j]);
    }
    #pragma unroll
    for (int j = 0; j < 9; ++j) h2[j] = fmaxf(h2[j], 0.f);

    float o[16];
    #pragma unroll
    for (int k = 0; k < 16; ++k) o[k] = fxb3[k];
    #pragma unroll
    for (int j = 0; j < 9; ++j) {
        const float hj = h2[j];
        #pragma unroll
        for (int k = 0; k < 16; ++k) o[k] = fmaf(hj, fxW3[j * 16 + k], o[k]);
    }

    float4* po = reinterpret_cast<float4*>(Xout + (size_t)n * 16);
    #pragma unroll
    for (int q = 0; q < 4; ++q) {
        float4 v;
        v.x = o[4*q]; v.y = o[4*q+1]; v.z = o[4*q+2]; v.w = o[4*q+3];
        po[q] = v;
    }

    // base1 / base_s for NEXT round's edge kernel
    float bb[9];
    #pragma unroll
    for (int j = 0; j < 9; ++j) bb[j] = feb1[j];
    #pragma unroll
    for (int i = 0; i < 16; ++i) {
        const float xi = o[i];
        #pragma unroll
        for (int j = 0; j < 9; ++j) bb[j] = fmaf(xi, feW1[i * 9 + j], bb[j]);
    }
    float* bp = base1out + (size_t)n * 12;
    #pragma unroll
    for (int j = 0; j < 9; ++j) bp[j] = bb[j];

    float cc[9];
    #pragma unroll
    for (int j = 0; j < 9; ++j) cc[j] = 0.f;
    #pragma unroll
    for (int i = 0; i < 16; ++i) {
        const float xi = o[i];
        #pragma unroll
        for (int j = 0; j < 9; ++j) cc[j] = fmaf(xi, feW1[(16 + i) * 9 + j], cc[j]);
    }
    float* sp = basesout + (size_t)n * 16;
    #pragma unroll
    for (int j = 0; j < 9; ++j) sp[j] = cc[j];
}

extern "C" void kernel_launch(void* const* d_in, const int* in_sizes, int n_in,
                              void* d_out, int out_size, void* d_ws, size_t ws_size,
                              hipStream_t stream)
{
    (void)in_sizes; (void)n_in; (void)out_size; (void)ws_size;
    const float* X0   = (const float*)d_in[0];
    const int*   esrc = (const int*)d_in[1];
    const int*   edst = (const int*)d_in[2];
    const float* feW1 = (const float*)d_in[3];
    const float* feb1 = (const float*)d_in[4];
    const float* feW2 = (const float*)d_in[5];
    const float* feb2 = (const float*)d_in[6];
    const float* feW3 = (const float*)d_in[7];
    const float* feb3 = (const float*)d_in[8];
    const float* fxW1 = (const float*)d_in[9];
    const float* fxb1 = (const float*)d_in[10];
    const float* fxW2 = (const float*)d_in[11];
    const float* fxb2 = (const float*)d_in[12];
    const float* fxW3 = (const float*)d_in[13];
    const float* fxb3 = (const float*)d_in[14];
    float* out = (float*)d_out;

    // workspace layout (floats unless noted). total ~44 MB. all 64B-aligned:
    // NN*12*4 = 4.8e6 B and NN*16*4 = 6.4e6 B are multiples of 64.
    float* base1  = (float*)d_ws;                         // NN*12
    float* bases  = base1 + (size_t)NN * 12;              // NN*16 (64B rows)
    float* mb     = bases + (size_t)NN * 16;              // NN*16 (64B rows)
    int* gcursor  = (int*)(mb + (size_t)NN * 16);         // NBK (padded to 1024)
    unsigned* sed = (unsigned*)(gcursor + 1024);          // NBK*SLOT u32 = 25.6MB

    const dim3 thr(256);
    const dim3 gS(NBLK_SORT);          // 782
    const dim3 gL(NBK);                // 782
    const dim3 gE(NBK * BPB);          // 18768
    const dim3 gN(NB_NODE);            // 391

    // ---- two-level sort (once per launch) ----
    hipMemsetAsync(gcursor, 0, NBK * sizeof(int), stream);
    bsort_k<<<gS, thr, 0, stream>>>(esrc, edst, gcursor, sed);
    lsort_k<<<gL, dim3(512), 0, stream>>>(sed, gcursor);

    // ---- round 0 ----
    base_k<<<gN, thr, 0, stream>>>(X0, feW1, feb1, base1, bases, mb);
    edge12_k<<<gE, thr, 0, stream>>>(base1, bases, sed, gcursor, feW2, feb2, mb);
    node10_k<<<gN, thr, 0, stream>>>(X0, mb, fxW1, fxb1, fxW2, fxb2, fxW3, fxb3,
                                     feW1, feb1, feW3, feb3, out, base1, bases);
    // ---- round 1 (node updates out in place; edge never reads X) ----
    edge12_k<<<gE, thr, 0, stream>>>(base1, bases, sed, gcursor, feW2, feb2, mb);
    node10_k<<<gN, thr, 0, stream>>>(out, mb, fxW1, fxb1, fxW2, fxb2, fxW3, fxb3,
                                     feW1, feb1, feW3, feb3, out, base1, bases);
    // ---- round 2 ----
    edge12_k<<<gE, thr, 0, stream>>>(base1, bases, sed, gcursor, feW2, feb2, mb);
    node10_k<<<gN, thr, 0, stream>>>(out, mb, fxW1, fxb1, fxW2, fxb2, fxW3, fxb3,
                                     feW1, feb1, feW3, feb3, out, base1, bases);
}